// Round 2
// baseline (678.234 us; speedup 1.0000x reference)
//
#include <hip/hip_runtime.h>
#include <math.h>

#define BIGV 10000000.0f
#define BIGS 1.0e8f            // sentinel in scaled units (only needs exp2(m-BIGS)==0)
#define TFULL 1024
#define TSD   1022
#define NBINS 64
#define CCH   31               // diagonals per barrier chunk; ring 64 >= 2*CCH+2

// ---------------- shared memory layouts (union, <64KB) ----------------
struct SmemDtw {
  float ys[1024];              // pre-scaled y (or its 2nd derivative)
  float bnd[16][64];           // per-wave boundary ring (lane-63 dk values)
};
struct SmemFused {
  float xr[1024], yr[1024];
  float fmp[5 * 1024], fmt[5 * 1024];   // also aliased for sdx/sdy before wavelet
  float aA[512], aB[512];
  float part[2048];
  float hx[NBINS], hy[NBINS];
  float red[16];
  float energy[8];
};
union SmemU { SmemDtw d; SmemFused f; };

// ---------------- reductions ----------------
__device__ __forceinline__ float waveReduceSum(float v) {
#pragma unroll
  for (int o = 32; o > 0; o >>= 1) v += __shfl_xor(v, o, 64);
  return v;
}

template <int OP>  // 0=sum 1=min 2=max
__device__ __forceinline__ float comb2(float a, float b) {
  if (OP == 0) return a + b;
  if (OP == 1) return fminf(a, b);
  return fmaxf(a, b);
}

template <int OP>
__device__ float blockReduce(float v, float* red, int tid) {
#pragma unroll
  for (int o = 32; o > 0; o >>= 1) v = comb2<OP>(v, __shfl_xor(v, o, 64));
  __syncthreads();
  if ((tid & 63) == 0) red[tid >> 6] = v;
  __syncthreads();
  if (tid == 0) {
    float r = red[0];
#pragma unroll
    for (int w = 1; w < 16; ++w) r = comb2<OP>(r, red[w]);
    red[0] = r;
  }
  __syncthreads();
  return red[0];
}

// ---------------- cdf_variance partial (per batch row) ----------------
__device__ float cdf_pair(const float* X, const float* Y, int N, SmemFused& s, int tid) {
  float xlo = 3.4e38f, xhi = -3.4e38f, ylo = 3.4e38f, yhi = -3.4e38f;
  for (int i = tid; i < N; i += 1024) {
    float xv = X[i], yv = Y[i];
    xlo = fminf(xlo, xv); xhi = fmaxf(xhi, xv);
    ylo = fminf(ylo, yv); yhi = fmaxf(yhi, yv);
  }
  xlo = blockReduce<1>(xlo, s.red, tid);
  xhi = blockReduce<2>(xhi, s.red, tid);
  ylo = blockReduce<1>(ylo, s.red, tid);
  yhi = blockReduce<2>(yhi, s.red, tid);
  float xinv = 1.f / (xhi - xlo + 1e-6f);
  float yinv = 1.f / (yhi - ylo + 1e-6f);

  int bin = tid >> 4, sub = tid & 15;
  float c = (float)bin * (1.f / 63.f);
  float hxp = 0.f, hyp = 0.f;
  for (int i = sub; i < N; i += 16) {
    float dx = (X[i] - xlo) * xinv - c;
    float dy = (Y[i] - ylo) * yinv - c;
    hxp += __expf(-200.f * dx * dx);   // exp(-0.5*(d/0.05)^2)
    hyp += __expf(-200.f * dy * dy);
  }
  s.part[tid] = hxp;
  s.part[1024 + tid] = hyp;
  __syncthreads();
  if (tid < NBINS) {
    float hx = 1e-6f, hy = 1e-6f;
#pragma unroll
    for (int t = 0; t < 16; ++t) {
      hx += s.part[tid * 16 + t];
      hy += s.part[1024 + tid * 16 + t];
    }
    s.hx[tid] = hx; s.hy[tid] = hy;
  }
  __syncthreads();
  if (tid == 0) {
    float totx = 0.f, toty = 0.f;
    for (int b2 = 0; b2 < NBINS; ++b2) { totx += s.hx[b2]; toty += s.hy[b2]; }
    float ix = 1.f / totx, iy = 1.f / toty;
    float cx = 0.f, cy = 0.f;
    for (int b2 = 0; b2 < NBINS; ++b2) {
      cx += s.hx[b2] * ix; cy += s.hy[b2] * iy;
      s.hx[b2] = cx; s.hy[b2] = cy;
    }
  }
  __syncthreads();
  float p = 0.f;
  if (tid < NBINS) { float d = s.hx[tid] - s.hy[tid]; p = d * d; }
  return blockReduce<0>(p, s.red, tid);  // caller divides by B*BINS
}

// ---------------- db4 wavelet map (writes fm[5][1024], zero-padded) ----------------
__device__ void wavelet_map(const float* row1024, float* fm, SmemFused& s, int tid, bool doEnergy) {
  const float LOF[8] = {-0.010597401784997278f, 0.032883011666982945f, 0.030841381835986965f,
                        -0.18703481171888114f, -0.02798376941698385f, 0.6308807679295904f,
                        0.7148465705525415f, 0.23037781330885523f};
  const float HIF[8] = {0.23037781330885523f, -0.7148465705525415f, 0.6308807679295904f,
                        0.02798376941698385f, -0.18703481171888114f, -0.030841381835986965f,
                        0.032883011666982945f, 0.010597401784997278f};
  const float* ain = row1024;
  int Lin = 1024;
  for (int lvl = 0; lvl < 5; ++lvl) {
    int Lout = Lin >> 1;
    float* aout = (lvl & 1) ? s.aA : s.aB;
    float d = 0.f, a = 0.f;
    if (tid < Lout) {
#pragma unroll
      for (int kk = 0; kk < 8; ++kk) {
        int idx = 2 * tid + kk - 3;   // stride 2, SAME pad (lo=3)
        float v = (idx >= 0 && idx < Lin) ? ain[idx] : 0.f;
        d = fmaf(v, HIF[kk], d);
        a = fmaf(v, LOF[kk], a);
      }
      aout[tid] = a;
    }
    fm[lvl * 1024 + tid] = (tid < Lout) ? d : 0.f;
    if (doEnergy) {
      float e = (tid < Lout) ? fabsf(d) : 0.f;
      float se = blockReduce<0>(e, s.red, tid);
      if (tid == 0) s.energy[lvl] = se * (1.f / 1024.f);
    }
    __syncthreads();
    ain = aout; Lin = Lout;
  }
}

// ---------------- main fused kernel: 192 blocks x 1024 threads ----------------
__global__ __launch_bounds__(1024)
void mdl_main(const float* __restrict__ pred, const float* __restrict__ tgt,
              float* __restrict__ ws) {
  __shared__ SmemU sm;
  const int blk = blockIdx.x;
  const int tid = threadIdx.x;

  if (blk < 128) {
    // =================== soft-DTW: chunk-pipelined wavefront ===================
    // Scaled units: u = R / (gamma*ln2); cost_scaled = ((x-y)*SQ)^2, SQ = sqrt(10/ln2).
    // softmin_scaled = mn - log2(1 + 2^(mn-md) + 2^(mn-mx)).
    SmemDtw& s = sm.d;
    const int mode = blk >> 6;          // 0: raw (T=1024), 1: second derivative (T=1022)
    const int b = blk & 63;
    const int T = mode ? TSD : TFULL;
    const float* xr = pred + b * 1024;
    const float* yr = tgt + b * 1024;
    const float SQ = 3.79828185f;       // sqrt(10/ln2)

    float xv = 0.f;
    if (tid < T) {
      xv        = (mode ? (xr[tid + 2] - 2.f * xr[tid + 1] + xr[tid]) : xr[tid]) * SQ;
      s.ys[tid] = (mode ? (yr[tid + 2] - 2.f * yr[tid + 1] + yr[tid]) : yr[tid]) * SQ;
    }
    {
      float* bf = &s.bnd[0][0];
      for (int i = tid; i < 16 * 64; i += 1024) bf[i] = BIGS;
    }
    __syncthreads();

    const int w = tid >> 6, lane = tid & 63;
    const unsigned Tc = (tid < T) ? (unsigned)T : 0u;  // for valid test
    const float* ring = s.bnd[(w == 0) ? 0 : (w - 1)];
    float* myring = s.bnd[w];
    const int wlo = 64 * w + 2;          // first diagonal any lane of this wave is valid
    const int whi = 64 * w + 64 + T;     // last
    const int twoT = 2 * T;
    const int NC = (twoT - 1 + CCH - 1) / CCH;

    float prev1 = BIGS, prev2 = BIGS;    // own R at diag k-1, k-2

    for (int m = 0; m < NC + 15; ++m) {
      const int c = m - w;
      if (c >= 0 && c < NC) {
        int k0 = 2 + c * CCH;
        int k1 = k0 + CCH;
        if (k1 > twoT + 1) k1 = twoT + 1;
        if (k0 < wlo) k0 = wlo;
        if (k1 > whi + 1) k1 = whi + 1;
        if (k0 < k1) {
          // n2 = neighbor's value at k0-2 (its prev2 right now)
          float n2 = __shfl_up(prev2, 1);
          if (lane == 0)
            n2 = (w > 0) ? ring[(k0 - 2) & 63] : ((k0 == 2) ? 0.f : BIGS);
          for (int k = k0; k < k1; ++k) {
            float n1 = __shfl_up(prev1, 1);          // neighbor at k-1
            if (lane == 0)
              n1 = (w > 0) ? ring[(k - 1) & 63] : BIGS;
            int jm1 = k - tid - 2;                   // j-1
            int jidx = min(max(jm1, 0), T - 1);
            float diff = xv - s.ys[jidx];
            float cost = diff * diff;
            float mn = fminf(fminf(n1, prev1), n2);
            float md = __builtin_amdgcn_fmed3f(n1, prev1, n2);
            float mx = fmaxf(fmaxf(n1, prev1), n2);
            float e = 1.0f + exp2f(mn - md) + exp2f(mn - mx);
            float dk = cost + mn - log2f(e);
            bool valid = ((unsigned)jm1 < Tc);
            dk = valid ? dk : BIGS;
            if (lane == 63) myring[k & 63] = dk;     // boundary for next wave
            n2 = n1;
            prev2 = prev1;
            prev1 = dk;
          }
        }
      }
      __syncthreads();
    }
    if (tid == T - 1) ws[blk] = prev1 * 0.06931471806f;  // * gamma*ln2 -> unscaled
  } else {
    // =================== fused per-batch losses ===================
    SmemFused& s = sm.f;
    const int b = blk - 128;
    const float* xg = pred + b * 1024;
    const float* yg = tgt + b * 1024;
    s.xr[tid] = xg[tid];
    s.yr[tid] = yg[tid];
    __syncthreads();

    float* sdx = s.fmp;
    float* sdy = s.fmp + 1024;
    float sdxv = 0.f, sdyv = 0.f;
    if (tid < TSD) {
      sdxv = s.xr[tid + 2] - 2.f * s.xr[tid + 1] + s.xr[tid];
      sdyv = s.yr[tid + 2] - 2.f * s.yr[tid + 1] + s.yr[tid];
    }
    sdx[tid] = sdxv;
    sdy[tid] = sdyv;

    float spp = blockReduce<0>(fabsf(s.xr[tid]), s.red, tid);
    float spd = blockReduce<0>((tid < TSD) ? fabsf(sdxv) : 0.f, s.red, tid);

    float c1 = cdf_pair(s.xr, s.yr, 1024, s, tid);
    float c2 = cdf_pair(sdx, sdy, TSD, s, tid);

    wavelet_map(s.xr, s.fmp, s, tid, true);
    wavelet_map(s.yr, s.fmt, s, tid, false);

    __syncthreads();
    if (tid == 0) {
      float e[5] = {s.energy[0], s.energy[1], s.energy[2], s.energy[3], s.energy[4]};
      int peak = 0; float best = e[0];
#pragma unroll
      for (int l = 1; l < 5; ++l) if (e[l] > best) { best = e[l]; peak = l; }
      float tot = 0.f, sel = 0.f;
#pragma unroll
      for (int l = 0; l < 5; ++l) {
        tot += e[l];
        if (l >= peak - 2 && l <= peak + 2) sel += e[l];
      }
      s.energy[7] = 1.f - sel / (tot + 1e-6f);
    }
    __syncthreads();
    float fr = s.energy[7];

    float c3 = cdf_pair(s.fmp, s.fmt, 5120, s, tid);

    if (tid == 0) {
      float* o = ws + 256 + b * 8;
      o[0] = c1; o[1] = c2; o[2] = c3;
      o[3] = fr; o[4] = spp; o[5] = spd;
    }
  }
}

// ---------------- final combine: 1 block x 64 threads ----------------
__global__ void mdl_combine(const float* __restrict__ ws, float* __restrict__ out) {
  const int lane = threadIdx.x;
  float vt = ws[lane];               // dtw time partial (batch=lane)
  float vs = ws[64 + lane];          // dtw sd partial
  const float* p = ws + 256 + lane * 8;
  float c1 = p[0], c2 = p[1], c3 = p[2], fr = p[3], sp = p[4], spd = p[5];
  vt = waveReduceSum(vt);  vs = waveReduceSum(vs);
  c1 = waveReduceSum(c1);  c2 = waveReduceSum(c2);  c3 = waveReduceSum(c3);
  fr = waveReduceSum(fr);  sp = waveReduceSum(sp);  spd = waveReduceSum(spd);
  if (lane == 0) {
    float dtw_t = vt * (1.f / 64.f);
    float dtw_s = vs * (1.f / 64.f);
    float l_time = dtw_t + sp * (1.f / 65536.f) + c1 * (1.f / 4096.f);
    float l_sd   = dtw_s + spd * (1.f / 65408.f) + c2 * (1.f / 4096.f);
    float l_freq = fr * (1.f / 64.f) + c3 * (1.f / 4096.f);
    float total = 1.5f * l_time + 0.8f * l_freq + 1.2f * l_sd;
    out[0] = total; out[1] = l_time; out[2] = l_freq; out[3] = l_sd;
  }
}

extern "C" void kernel_launch(void* const* d_in, const int* in_sizes, int n_in,
                              void* d_out, int out_size, void* d_ws, size_t ws_size,
                              hipStream_t stream) {
  const float* pred = (const float*)d_in[0];
  const float* tgt  = (const float*)d_in[1];
  float* out = (float*)d_out;
  float* ws  = (float*)d_ws;
  mdl_main<<<dim3(192), dim3(1024), 0, stream>>>(pred, tgt, ws);
  mdl_combine<<<dim3(1), dim3(64), 0, stream>>>(ws, out);
}

// Round 3
// 629.794 us; speedup vs baseline: 1.0769x; 1.0769x over previous
//
#include <hip/hip_runtime.h>
#include <math.h>

#define BIGS  1.0e8f           // sentinel in scaled units
#define YPADV 12000.0f         // pad value: cost >= ~1.4e8 acts as BIG
#define TFULL 1024
#define TSD   1022
#define NBINS 64
#define CCH   31               // diagonals per barrier chunk; ring 64 >= 2*CCH+2
#define SQ    3.79828185f      // sqrt(1/(0.1*ln2)): cost_scaled = ((x-y)*SQ)^2
#define GAMLN2 0.069314718f    // 0.1*ln2: unscale factor

// ---------------- shared memory layouts (union, <64KB) ----------------
struct SmemDtw {
  float ys[1280];              // [128 front pad][1024 y][128 back pad], pre-scaled
  float bnd[8][64];            // per-wave boundary ring (lane-63 cell-B values)
};
struct SmemFused {
  float xr[1024], yr[1024];
  float fmp[5 * 1024], fmt[5 * 1024];   // fmp[0..2047] aliased for sdx/sdy early
  float aA[512], aB[512];
  float part[2048];
  float hx[NBINS], hy[NBINS];
  float red[8];
  float energy[8];
};
union SmemU { SmemDtw d; SmemFused f; };

// ---------------- reductions ----------------
__device__ __forceinline__ float waveReduceSum(float v) {
#pragma unroll
  for (int o = 32; o > 0; o >>= 1) v += __shfl_xor(v, o, 64);
  return v;
}

template <int OP>  // 0=sum 1=min 2=max
__device__ __forceinline__ float comb2(float a, float b) {
  if (OP == 0) return a + b;
  if (OP == 1) return fminf(a, b);
  return fmaxf(a, b);
}

template <int OP>
__device__ float blockReduce(float v, float* red, int tid) {
#pragma unroll
  for (int o = 32; o > 0; o >>= 1) v = comb2<OP>(v, __shfl_xor(v, o, 64));
  __syncthreads();
  if ((tid & 63) == 0) red[tid >> 6] = v;
  __syncthreads();
  if (tid == 0) {
    float r = red[0];
#pragma unroll
    for (int w = 1; w < 8; ++w) r = comb2<OP>(r, red[w]);
    red[0] = r;
  }
  __syncthreads();
  return red[0];
}

// ---------------- cdf_variance partial (512 threads) ----------------
__device__ float cdf_pair(const float* X, const float* Y, int N, SmemFused& s, int tid) {
  float xlo = 3.4e38f, xhi = -3.4e38f, ylo = 3.4e38f, yhi = -3.4e38f;
  for (int i = tid; i < N; i += 512) {
    float xv = X[i], yv = Y[i];
    xlo = fminf(xlo, xv); xhi = fmaxf(xhi, xv);
    ylo = fminf(ylo, yv); yhi = fmaxf(yhi, yv);
  }
  xlo = blockReduce<1>(xlo, s.red, tid);
  xhi = blockReduce<2>(xhi, s.red, tid);
  ylo = blockReduce<1>(ylo, s.red, tid);
  yhi = blockReduce<2>(yhi, s.red, tid);
  float xinv = 1.f / (xhi - xlo + 1e-6f);
  float yinv = 1.f / (yhi - ylo + 1e-6f);

  int bin = tid >> 3, sub = tid & 7;          // 64 bins x 8 sub-threads
  float c = (float)bin * (1.f / 63.f);
  float hxp = 0.f, hyp = 0.f;
  for (int i = sub; i < N; i += 8) {
    float dx = (X[i] - xlo) * xinv - c;
    float dy = (Y[i] - ylo) * yinv - c;
    hxp += __expf(-200.f * dx * dx);
    hyp += __expf(-200.f * dy * dy);
  }
  s.part[tid] = hxp;
  s.part[1024 + tid] = hyp;
  __syncthreads();
  if (tid < NBINS) {
    float hx = 1e-6f, hy = 1e-6f;
#pragma unroll
    for (int t = 0; t < 8; ++t) {
      hx += s.part[tid * 8 + t];
      hy += s.part[1024 + tid * 8 + t];
    }
    s.hx[tid] = hx; s.hy[tid] = hy;
  }
  __syncthreads();
  if (tid == 0) {
    float totx = 0.f, toty = 0.f;
    for (int b2 = 0; b2 < NBINS; ++b2) { totx += s.hx[b2]; toty += s.hy[b2]; }
    float ix = 1.f / totx, iy = 1.f / toty;
    float cx = 0.f, cy = 0.f;
    for (int b2 = 0; b2 < NBINS; ++b2) {
      cx += s.hx[b2] * ix; cy += s.hy[b2] * iy;
      s.hx[b2] = cx; s.hy[b2] = cy;
    }
  }
  __syncthreads();
  float p = 0.f;
  if (tid < NBINS) { float d = s.hx[tid] - s.hy[tid]; p = d * d; }
  return blockReduce<0>(p, s.red, tid);
}

// ---------------- db4 wavelet map (512 threads) ----------------
__device__ void wavelet_map(const float* row1024, float* fm, SmemFused& s, int tid, bool doEnergy) {
  const float LOF[8] = {-0.010597401784997278f, 0.032883011666982945f, 0.030841381835986965f,
                        -0.18703481171888114f, -0.02798376941698385f, 0.6308807679295904f,
                        0.7148465705525415f, 0.23037781330885523f};
  const float HIF[8] = {0.23037781330885523f, -0.7148465705525415f, 0.6308807679295904f,
                        0.02798376941698385f, -0.18703481171888114f, -0.030841381835986965f,
                        0.032883011666982945f, 0.010597401784997278f};
  const float* ain = row1024;
  int Lin = 1024;
  for (int lvl = 0; lvl < 5; ++lvl) {
    int Lout = Lin >> 1;                 // 512,256,128,64,32
    float* aout = (lvl & 1) ? s.aA : s.aB;
    float d = 0.f, a = 0.f;
    if (tid < Lout) {
#pragma unroll
      for (int kk = 0; kk < 8; ++kk) {
        int idx = 2 * tid + kk - 3;      // stride 2, SAME pad
        float v = (idx >= 0 && idx < Lin) ? ain[idx] : 0.f;
        d = fmaf(v, HIF[kk], d);
        a = fmaf(v, LOF[kk], a);
      }
      aout[tid] = a;
    }
    fm[lvl * 1024 + tid] = (tid < Lout) ? d : 0.f;
    fm[lvl * 1024 + tid + 512] = 0.f;
    if (doEnergy) {
      float e = (tid < Lout) ? fabsf(d) : 0.f;
      float se = blockReduce<0>(e, s.red, tid);
      if (tid == 0) s.energy[lvl] = se * (1.f / 1024.f);
    }
    __syncthreads();
    ain = aout; Lin = Lout;
  }
}

// ---------------- main fused kernel: 192 blocks x 512 threads ----------------
__global__ __launch_bounds__(512)
void mdl_main(const float* __restrict__ pred, const float* __restrict__ tgt,
              float* __restrict__ ws) {
  __shared__ SmemU sm;
  const int blk = blockIdx.x;
  const int tid = threadIdx.x;

  if (blk < 128) {
    // ============ soft-DTW: G=2 coarsened chunk-pipelined wavefront ============
    SmemDtw& s = sm.d;
    const int mode = blk >> 6;          // 0: raw (T=1024), 1: 2nd derivative (T=1022)
    const int b = blk & 63;
    const int T = mode ? TSD : TFULL;
    const float* xr = pred + b * 1024;
    const float* yr = tgt + b * 1024;

    // stage y (pre-scaled) with BIG pads; fill rings
    for (int i = tid; i < 1280; i += 512) {
      int j = i - 128;                   // 0-based y index
      float v = YPADV;
      if (j >= 0 && j < T)
        v = (mode ? (yr[j + 2] - 2.f * yr[j + 1] + yr[j]) : yr[j]) * SQ;
      s.ys[i] = v;
    }
    for (int i = tid; i < 8 * 64; i += 512) (&s.bnd[0][0])[i] = BIGS;

    // x registers: thread owns rows iA=2t+1, iB=2t+2 (1-based)
    const int iA = 2 * tid + 1, iB = iA + 1;
    float xA = YPADV, xB = YPADV;
    if (iA <= T) xA = (mode ? (xr[iA + 1] - 2.f * xr[iA] + xr[iA - 1]) : xr[iA - 1]) * SQ;
    if (iB <= T) xB = (mode ? (xr[iB + 1] - 2.f * xr[iB] + xr[iB - 1]) : xr[iB - 1]) * SQ;
    __syncthreads();

    const int w = tid >> 6, lane = tid & 63;
    const bool lane0 = (lane == 0);
    const int bpaddr = ((lane + 63) & 63) << 2;     // bpermute: pull from lane-1
    const float* ring = s.bnd[(w > 0) ? (w - 1) : 0];
    float* wring = s.bnd[w];
    const int wlo = 128 * w + 2;
    const int whi = min(128 * w + 128, T) + T;      // last diag this wave computes
    const int twoT = 2 * T;
    const int NC = (twoT - 1 + CCH - 1) / CCH;

    float a1 = BIGS, a2 = BIGS, b1 = BIGS;
    float nprev = (w == 0 && lane0) ? 0.f : BIGS;   // R[0,0] seed

    for (int m = 0; m < NC + 8; ++m) {
      const int c = m - w;
      if (c >= 0 && c < NC) {
        int k0 = 2 + c * CCH, k1 = k0 + CCH;
        if (k1 > twoT + 1) k1 = twoT + 1;
        if (k0 < wlo) k0 = wlo;
        if (k1 > whi + 1) k1 = whi + 1;
        if (k0 < k1) {
          int yidx = k0 - 2 * tid - 2 + 128;        // LDS index of yA at k0
          float yB = s.ys[yidx - 1];                // prime: yA at k0-1
          for (int k = k0; k < k1; ++k) {
            float yA = s.ys[yidx];
            float ringv = BIGS;
            if (w > 0) ringv = ring[(k - 1) & 63];  // broadcast read
            float nb = __int_as_float(
                __builtin_amdgcn_ds_bpermute(bpaddr, __float_as_int(b1)));
            nb = lane0 ? ringv : nb;                // patch wave boundary
            // cell B (row iB): deps a1,b1,a2 (all registers)
            float dB = xB - yB;
            float mnB = fminf(fminf(a1, b1), a2);
            float mdB = __builtin_amdgcn_fmed3f(a1, b1, a2);
            float mxB = fmaxf(fmaxf(a1, b1), a2);
            float eB = 1.f + exp2f(mnB - mdB) + exp2f(mnB - mxB);
            float dkB = fmaf(dB, dB, mnB) - log2f(eB);
            // cell A (row iA): deps nb, a1, nprev
            float dA = xA - yA;
            float mnA = fminf(fminf(nb, a1), nprev);
            float mdA = __builtin_amdgcn_fmed3f(nb, a1, nprev);
            float mxA = fmaxf(fmaxf(nb, a1), nprev);
            float eA = 1.f + exp2f(mnA - mdA) + exp2f(mnA - mxA);
            float dkA = fmaf(dA, dA, mnA) - log2f(eA);
            if (lane == 63) wring[k & 63] = dkB;    // boundary for next wave
            nprev = nb; a2 = a1; a1 = dkA; b1 = dkB;
            yB = yA; ++yidx;
          }
        }
      }
      __syncthreads();
    }
    // answer: R[T,T] = cell B of thread (T-2)/2, still in b1 (whi clamped to iB+T)
    if (tid == ((T - 2) >> 1)) ws[blk] = b1 * GAMLN2;
  } else {
    // =================== fused per-batch losses (512 threads) ===================
    SmemFused& s = sm.f;
    const int b = blk - 128;
    const float* xg = pred + b * 1024;
    const float* yg = tgt + b * 1024;
    s.xr[tid] = xg[tid];        s.yr[tid] = yg[tid];
    s.xr[tid + 512] = xg[tid + 512]; s.yr[tid + 512] = yg[tid + 512];
    __syncthreads();

    // second derivative rows, aliased onto fmp region
    float* sdx = s.fmp;
    float* sdy = s.fmp + 1024;
    float spdacc = 0.f;
    for (int i = tid; i < TSD; i += 512) {
      float a = s.xr[i + 2] - 2.f * s.xr[i + 1] + s.xr[i];
      float cc = s.yr[i + 2] - 2.f * s.yr[i + 1] + s.yr[i];
      sdx[i] = a; sdy[i] = cc;
      spdacc += fabsf(a);
    }
    float spp = blockReduce<0>(fabsf(s.xr[tid]) + fabsf(s.xr[tid + 512]), s.red, tid);
    float spd = blockReduce<0>(spdacc, s.red, tid);   // barriers make sdx/sdy visible

    float c1 = cdf_pair(s.xr, s.yr, 1024, s, tid);
    float c2 = cdf_pair(sdx, sdy, TSD, s, tid);

    wavelet_map(s.xr, s.fmp, s, tid, true);
    wavelet_map(s.yr, s.fmt, s, tid, false);

    __syncthreads();
    if (tid == 0) {
      float e[5] = {s.energy[0], s.energy[1], s.energy[2], s.energy[3], s.energy[4]};
      int peak = 0; float best = e[0];
#pragma unroll
      for (int l = 1; l < 5; ++l) if (e[l] > best) { best = e[l]; peak = l; }
      float tot = 0.f, sel = 0.f;
#pragma unroll
      for (int l = 0; l < 5; ++l) {
        tot += e[l];
        if (l >= peak - 2 && l <= peak + 2) sel += e[l];
      }
      s.energy[7] = 1.f - sel / (tot + 1e-6f);
    }
    __syncthreads();
    float fr = s.energy[7];

    float c3 = cdf_pair(s.fmp, s.fmt, 5120, s, tid);

    if (tid == 0) {
      float* o = ws + 256 + b * 8;
      o[0] = c1; o[1] = c2; o[2] = c3;
      o[3] = fr; o[4] = spp; o[5] = spd;
    }
  }
}

// ---------------- final combine: 1 block x 64 threads ----------------
__global__ void mdl_combine(const float* __restrict__ ws, float* __restrict__ out) {
  const int lane = threadIdx.x;
  float vt = ws[lane];               // dtw time partial (batch=lane)
  float vs = ws[64 + lane];          // dtw sd partial
  const float* p = ws + 256 + lane * 8;
  float c1 = p[0], c2 = p[1], c3 = p[2], fr = p[3], sp = p[4], spd = p[5];
  vt = waveReduceSum(vt);  vs = waveReduceSum(vs);
  c1 = waveReduceSum(c1);  c2 = waveReduceSum(c2);  c3 = waveReduceSum(c3);
  fr = waveReduceSum(fr);  sp = waveReduceSum(sp);  spd = waveReduceSum(spd);
  if (lane == 0) {
    float dtw_t = vt * (1.f / 64.f);
    float dtw_s = vs * (1.f / 64.f);
    float l_time = dtw_t + sp * (1.f / 65536.f) + c1 * (1.f / 4096.f);
    float l_sd   = dtw_s + spd * (1.f / 65408.f) + c2 * (1.f / 4096.f);
    float l_freq = fr * (1.f / 64.f) + c3 * (1.f / 4096.f);
    float total = 1.5f * l_time + 0.8f * l_freq + 1.2f * l_sd;
    out[0] = total; out[1] = l_time; out[2] = l_freq; out[3] = l_sd;
  }
}

extern "C" void kernel_launch(void* const* d_in, const int* in_sizes, int n_in,
                              void* d_out, int out_size, void* d_ws, size_t ws_size,
                              hipStream_t stream) {
  const float* pred = (const float*)d_in[0];
  const float* tgt  = (const float*)d_in[1];
  float* out = (float*)d_out;
  float* ws  = (float*)d_ws;
  mdl_main<<<dim3(192), dim3(512), 0, stream>>>(pred, tgt, ws);
  mdl_combine<<<dim3(1), dim3(64), 0, stream>>>(ws, out);
}

// Round 4
// 564.640 us; speedup vs baseline: 1.2012x; 1.1154x over previous
//
#include <hip/hip_runtime.h>
#include <math.h>

#define BIGS  1.0e8f           // sentinel in scaled units
#define YPADV 12000.0f         // pad value: cost >= ~1.4e8 acts as BIG
#define TFULL 1024
#define TSD   1022
#define NBINS 64
#define CCH   31               // diagonals per barrier chunk; ring 64 >= 2*CCH+2
#define SQ    3.79828185f      // sqrt(1/(0.1*ln2)): cost_scaled = ((x-y)*SQ)^2
#define GAMLN2 0.069314718f    // 0.1*ln2: unscale factor

// ---------------- shared memory layouts (union, <64KB) ----------------
struct SmemDtw {
  float ys[1280];              // [128 front pad][1024 y][128 back pad], pre-scaled
  float bnd[8][64];            // per-wave boundary ring (lane-63 cell-B values)
};
struct SmemFused {
  float xr[1024], yr[1024];
  float fmp[5 * 1024], fmt[5 * 1024];   // fmp[0..2047] aliased for sdx/sdy early
  float aA[512], aB[512];
  float part[2048];
  float hx[NBINS], hy[NBINS];
  float red[8];
  float energy[8];
};
union SmemU { SmemDtw d; SmemFused f; };

// ---------------- reductions ----------------
__device__ __forceinline__ float waveReduceSum(float v) {
#pragma unroll
  for (int o = 32; o > 0; o >>= 1) v += __shfl_xor(v, o, 64);
  return v;
}

template <int OP>  // 0=sum 1=min 2=max
__device__ __forceinline__ float comb2(float a, float b) {
  if (OP == 0) return a + b;
  if (OP == 1) return fminf(a, b);
  return fmaxf(a, b);
}

template <int OP>
__device__ float blockReduce(float v, float* red, int tid) {
#pragma unroll
  for (int o = 32; o > 0; o >>= 1) v = comb2<OP>(v, __shfl_xor(v, o, 64));
  __syncthreads();
  if ((tid & 63) == 0) red[tid >> 6] = v;
  __syncthreads();
  if (tid == 0) {
    float r = red[0];
#pragma unroll
    for (int w = 1; w < 8; ++w) r = comb2<OP>(r, red[w]);
    red[0] = r;
  }
  __syncthreads();
  return red[0];
}

// ---------------- cdf_variance partial (512 threads) ----------------
__device__ float cdf_pair(const float* X, const float* Y, int N, SmemFused& s, int tid) {
  float xlo = 3.4e38f, xhi = -3.4e38f, ylo = 3.4e38f, yhi = -3.4e38f;
  for (int i = tid; i < N; i += 512) {
    float xv = X[i], yv = Y[i];
    xlo = fminf(xlo, xv); xhi = fmaxf(xhi, xv);
    ylo = fminf(ylo, yv); yhi = fmaxf(yhi, yv);
  }
  xlo = blockReduce<1>(xlo, s.red, tid);
  xhi = blockReduce<2>(xhi, s.red, tid);
  ylo = blockReduce<1>(ylo, s.red, tid);
  yhi = blockReduce<2>(yhi, s.red, tid);
  float xinv = 1.f / (xhi - xlo + 1e-6f);
  float yinv = 1.f / (yhi - ylo + 1e-6f);

  int bin = tid >> 3, sub = tid & 7;          // 64 bins x 8 sub-threads
  float c = (float)bin * (1.f / 63.f);
  float hxp = 0.f, hyp = 0.f;
  for (int i = sub; i < N; i += 8) {
    float dx = (X[i] - xlo) * xinv - c;
    float dy = (Y[i] - ylo) * yinv - c;
    hxp += __expf(-200.f * dx * dx);
    hyp += __expf(-200.f * dy * dy);
  }
  s.part[tid] = hxp;
  s.part[1024 + tid] = hyp;
  __syncthreads();
  if (tid < NBINS) {
    float hx = 1e-6f, hy = 1e-6f;
#pragma unroll
    for (int t = 0; t < 8; ++t) {
      hx += s.part[tid * 8 + t];
      hy += s.part[1024 + tid * 8 + t];
    }
    s.hx[tid] = hx; s.hy[tid] = hy;
  }
  __syncthreads();
  if (tid == 0) {
    float totx = 0.f, toty = 0.f;
    for (int b2 = 0; b2 < NBINS; ++b2) { totx += s.hx[b2]; toty += s.hy[b2]; }
    float ix = 1.f / totx, iy = 1.f / toty;
    float cx = 0.f, cy = 0.f;
    for (int b2 = 0; b2 < NBINS; ++b2) {
      cx += s.hx[b2] * ix; cy += s.hy[b2] * iy;
      s.hx[b2] = cx; s.hy[b2] = cy;
    }
  }
  __syncthreads();
  float p = 0.f;
  if (tid < NBINS) { float d = s.hx[tid] - s.hy[tid]; p = d * d; }
  return blockReduce<0>(p, s.red, tid);
}

// ---------------- db4 wavelet map (512 threads) ----------------
__device__ void wavelet_map(const float* row1024, float* fm, SmemFused& s, int tid, bool doEnergy) {
  const float LOF[8] = {-0.010597401784997278f, 0.032883011666982945f, 0.030841381835986965f,
                        -0.18703481171888114f, -0.02798376941698385f, 0.6308807679295904f,
                        0.7148465705525415f, 0.23037781330885523f};
  const float HIF[8] = {0.23037781330885523f, -0.7148465705525415f, 0.6308807679295904f,
                        0.02798376941698385f, -0.18703481171888114f, -0.030841381835986965f,
                        0.032883011666982945f, 0.010597401784997278f};
  const float* ain = row1024;
  int Lin = 1024;
  for (int lvl = 0; lvl < 5; ++lvl) {
    int Lout = Lin >> 1;                 // 512,256,128,64,32
    float* aout = (lvl & 1) ? s.aA : s.aB;
    float d = 0.f, a = 0.f;
    if (tid < Lout) {
#pragma unroll
      for (int kk = 0; kk < 8; ++kk) {
        int idx = 2 * tid + kk - 3;      // stride 2, SAME pad
        float v = (idx >= 0 && idx < Lin) ? ain[idx] : 0.f;
        d = fmaf(v, HIF[kk], d);
        a = fmaf(v, LOF[kk], a);
      }
      aout[tid] = a;
    }
    fm[lvl * 1024 + tid] = (tid < Lout) ? d : 0.f;
    fm[lvl * 1024 + tid + 512] = 0.f;
    if (doEnergy) {
      float e = (tid < Lout) ? fabsf(d) : 0.f;
      float se = blockReduce<0>(e, s.red, tid);
      if (tid == 0) s.energy[lvl] = se * (1.f / 1024.f);
    }
    __syncthreads();
    ain = aout; Lin = Lout;
  }
}

// ---------------- main fused kernel: 192 blocks x 512 threads ----------------
__global__ __launch_bounds__(512)
void mdl_main(const float* __restrict__ pred, const float* __restrict__ tgt,
              float* __restrict__ ws) {
  __shared__ SmemU sm;
  const int blk = blockIdx.x;
  const int tid = threadIdx.x;

  if (blk < 128) {
    // ============ soft-DTW: G=2 coarsened, DPP wave_shr neighbor exchange ============
    SmemDtw& s = sm.d;
    const int mode = blk >> 6;          // 0: raw (T=1024), 1: 2nd derivative (T=1022)
    const int b = blk & 63;
    const int T = mode ? TSD : TFULL;
    const float* xr = pred + b * 1024;
    const float* yr = tgt + b * 1024;

    // stage y (pre-scaled) with BIG pads; fill rings
    for (int i = tid; i < 1280; i += 512) {
      int j = i - 128;                   // 0-based y index
      float v = YPADV;
      if (j >= 0 && j < T)
        v = (mode ? (yr[j + 2] - 2.f * yr[j + 1] + yr[j]) : yr[j]) * SQ;
      s.ys[i] = v;
    }
    for (int i = tid; i < 8 * 64; i += 512) (&s.bnd[0][0])[i] = BIGS;

    // x registers: thread owns rows iA=2t+1, iB=2t+2 (1-based)
    const int iA = 2 * tid + 1, iB = iA + 1;
    float xA = YPADV, xB = YPADV;
    if (iA <= T) xA = (mode ? (xr[iA + 1] - 2.f * xr[iA] + xr[iA - 1]) : xr[iA - 1]) * SQ;
    if (iB <= T) xB = (mode ? (xr[iB + 1] - 2.f * xr[iB] + xr[iB - 1]) : xr[iB - 1]) * SQ;
    __syncthreads();

    const int w = tid >> 6, lane = tid & 63;
    const bool hasRing = (w > 0);
    const float* ring = s.bnd[hasRing ? (w - 1) : 0];
    float* wring = s.bnd[w];
    const int wlo = 128 * w + 2;
    const int whi = min(128 * w + 128, T) + T;      // last diag this wave computes
    const int twoT = 2 * T;
    const int NC = (twoT - 1 + CCH - 1) / CCH;

    float a1 = BIGS, a2 = BIGS, b1 = BIGS;
    float nprev = (w == 0 && lane == 0) ? 0.f : BIGS;   // R[0,0] seed

    for (int m = 0; m < NC + 8; ++m) {
      const int c = m - w;
      if (c >= 0 && c < NC) {
        int k0 = 2 + c * CCH, k1 = k0 + CCH;
        if (k1 > twoT + 1) k1 = twoT + 1;
        if (k0 < wlo) k0 = wlo;
        if (k1 > whi + 1) k1 = whi + 1;
        if (k0 < k1) {
          int yidx = k0 - 2 * tid - 2 + 128;        // LDS index of yA at k0
          float yB = s.ys[yidx - 1];                // y for cell B at k0
          float yA = s.ys[yidx];                    // y for cell A at k0
          float rv = hasRing ? ring[(k0 - 1) & 63] : BIGS;  // boundary val for k0
          for (int k = k0; k < k1; ++k) {
            // prefetch next iteration's operands (off critical path)
            float yA_n = s.ys[yidx + 1];
            float rv_n = hasRing ? ring[k & 63] : BIGS;
            // neighbor exchange: lane l <- lane l-1's b1; lane 0 <- rv (old operand)
            float nb = __int_as_float(__builtin_amdgcn_update_dpp(
                __float_as_int(rv), __float_as_int(b1),
                0x138 /*WAVE_SHR1*/, 0xF, 0xF, false));
            // cell B (row iB): deps a1,b1,a2 (all registers)
            float dB = xB - yB;
            float mnB = fminf(fminf(a1, b1), a2);
            float mdB = __builtin_amdgcn_fmed3f(a1, b1, a2);
            float mxB = fmaxf(fmaxf(a1, b1), a2);
            float eB = 1.f + exp2f(mnB - mdB) + exp2f(mnB - mxB);
            float dkB = fmaf(dB, dB, mnB) - log2f(eB);
            // cell A (row iA): deps nb, a1, nprev
            float dA = xA - yA;
            float mnA = fminf(fminf(nb, a1), nprev);
            float mdA = __builtin_amdgcn_fmed3f(nb, a1, nprev);
            float mxA = fmaxf(fmaxf(nb, a1), nprev);
            float eA = 1.f + exp2f(mnA - mdA) + exp2f(mnA - mxA);
            float dkA = fmaf(dA, dA, mnA) - log2f(eA);
            if (lane == 63) wring[k & 63] = dkB;    // boundary for next wave
            nprev = nb; a2 = a1; a1 = dkA; b1 = dkB;
            yB = yA; yA = yA_n; rv = rv_n; ++yidx;
          }
        }
      }
      __syncthreads();
    }
    // answer: R[T,T] = cell B of thread (T-2)/2, still in b1 (whi clamped to iB+T)
    if (tid == ((T - 2) >> 1)) ws[blk] = b1 * GAMLN2;
  } else {
    // =================== fused per-batch losses (512 threads) ===================
    SmemFused& s = sm.f;
    const int b = blk - 128;
    const float* xg = pred + b * 1024;
    const float* yg = tgt + b * 1024;
    s.xr[tid] = xg[tid];        s.yr[tid] = yg[tid];
    s.xr[tid + 512] = xg[tid + 512]; s.yr[tid + 512] = yg[tid + 512];
    __syncthreads();

    // second derivative rows, aliased onto fmp region
    float* sdx = s.fmp;
    float* sdy = s.fmp + 1024;
    float spdacc = 0.f;
    for (int i = tid; i < TSD; i += 512) {
      float a = s.xr[i + 2] - 2.f * s.xr[i + 1] + s.xr[i];
      float cc = s.yr[i + 2] - 2.f * s.yr[i + 1] + s.yr[i];
      sdx[i] = a; sdy[i] = cc;
      spdacc += fabsf(a);
    }
    float spp = blockReduce<0>(fabsf(s.xr[tid]) + fabsf(s.xr[tid + 512]), s.red, tid);
    float spd = blockReduce<0>(spdacc, s.red, tid);   // barriers make sdx/sdy visible

    float c1 = cdf_pair(s.xr, s.yr, 1024, s, tid);
    float c2 = cdf_pair(sdx, sdy, TSD, s, tid);

    wavelet_map(s.xr, s.fmp, s, tid, true);
    wavelet_map(s.yr, s.fmt, s, tid, false);

    __syncthreads();
    if (tid == 0) {
      float e[5] = {s.energy[0], s.energy[1], s.energy[2], s.energy[3], s.energy[4]};
      int peak = 0; float best = e[0];
#pragma unroll
      for (int l = 1; l < 5; ++l) if (e[l] > best) { best = e[l]; peak = l; }
      float tot = 0.f, sel = 0.f;
#pragma unroll
      for (int l = 0; l < 5; ++l) {
        tot += e[l];
        if (l >= peak - 2 && l <= peak + 2) sel += e[l];
      }
      s.energy[7] = 1.f - sel / (tot + 1e-6f);
    }
    __syncthreads();
    float fr = s.energy[7];

    float c3 = cdf_pair(s.fmp, s.fmt, 5120, s, tid);

    if (tid == 0) {
      float* o = ws + 256 + b * 8;
      o[0] = c1; o[1] = c2; o[2] = c3;
      o[3] = fr; o[4] = spp; o[5] = spd;
    }
  }
}

// ---------------- final combine: 1 block x 64 threads ----------------
__global__ void mdl_combine(const float* __restrict__ ws, float* __restrict__ out) {
  const int lane = threadIdx.x;
  float vt = ws[lane];               // dtw time partial (batch=lane)
  float vs = ws[64 + lane];          // dtw sd partial
  const float* p = ws + 256 + lane * 8;
  float c1 = p[0], c2 = p[1], c3 = p[2], fr = p[3], sp = p[4], spd = p[5];
  vt = waveReduceSum(vt);  vs = waveReduceSum(vs);
  c1 = waveReduceSum(c1);  c2 = waveReduceSum(c2);  c3 = waveReduceSum(c3);
  fr = waveReduceSum(fr);  sp = waveReduceSum(sp);  spd = waveReduceSum(spd);
  if (lane == 0) {
    float dtw_t = vt * (1.f / 64.f);
    float dtw_s = vs * (1.f / 64.f);
    float l_time = dtw_t + sp * (1.f / 65536.f) + c1 * (1.f / 4096.f);
    float l_sd   = dtw_s + spd * (1.f / 65408.f) + c2 * (1.f / 4096.f);
    float l_freq = fr * (1.f / 64.f) + c3 * (1.f / 4096.f);
    float total = 1.5f * l_time + 0.8f * l_freq + 1.2f * l_sd;
    out[0] = total; out[1] = l_time; out[2] = l_freq; out[3] = l_sd;
  }
}

extern "C" void kernel_launch(void* const* d_in, const int* in_sizes, int n_in,
                              void* d_out, int out_size, void* d_ws, size_t ws_size,
                              hipStream_t stream) {
  const float* pred = (const float*)d_in[0];
  const float* tgt  = (const float*)d_in[1];
  float* out = (float*)d_out;
  float* ws  = (float*)d_ws;
  mdl_main<<<dim3(192), dim3(512), 0, stream>>>(pred, tgt, ws);
  mdl_combine<<<dim3(1), dim3(64), 0, stream>>>(ws, out);
}

// Round 5
// 454.319 us; speedup vs baseline: 1.4929x; 1.2428x over previous
//
#include <hip/hip_runtime.h>
#include <math.h>

#define BIGS  1.0e8f           // sentinel in scaled units
#define YPADV 12000.0f         // pad value: cost >= ~1.4e8 acts as BIG
#define TFULL 1024
#define TSD   1022
#define NBINS 64
#define CH    32               // diagonals per chunk (fully unrolled)
#define SQ    3.79828185f      // sqrt(1/(0.1*ln2)): cost_scaled = ((x-y)*SQ)^2
#define GAMLN2 0.069314718f    // 0.1*ln2: unscale factor

// ---------------- shared memory layouts (union, <64KB) ----------------
struct SmemDtw {
  float ys[1408];              // [128 front pad][1024 y][256 back pad], pre-scaled
  float bnd[8][3][32];         // per-wave chunk-indexed boundary buffers (mod 3)
};
struct SmemFused {
  float xr[1024], yr[1024];
  float fmp[5 * 1024], fmt[5 * 1024];   // fmp[0..2047] aliased for sdx/sdy early
  float aA[512], aB[512];
  float part[2048];
  float hx[NBINS], hy[NBINS];
  float red[8];
  float energy[8];
};
union SmemU { SmemDtw d; SmemFused f; };

// ---------------- reductions ----------------
__device__ __forceinline__ float waveReduceSum(float v) {
#pragma unroll
  for (int o = 32; o > 0; o >>= 1) v += __shfl_xor(v, o, 64);
  return v;
}

template <int OP>  // 0=sum 1=min 2=max
__device__ __forceinline__ float comb2(float a, float b) {
  if (OP == 0) return a + b;
  if (OP == 1) return fminf(a, b);
  return fmaxf(a, b);
}

template <int OP>
__device__ float blockReduce(float v, float* red, int tid) {
#pragma unroll
  for (int o = 32; o > 0; o >>= 1) v = comb2<OP>(v, __shfl_xor(v, o, 64));
  __syncthreads();
  if ((tid & 63) == 0) red[tid >> 6] = v;
  __syncthreads();
  if (tid == 0) {
    float r = red[0];
#pragma unroll
    for (int w = 1; w < 8; ++w) r = comb2<OP>(r, red[w]);
    red[0] = r;
  }
  __syncthreads();
  return red[0];
}

// ---------------- cdf_variance partial (512 threads) ----------------
__device__ float cdf_pair(const float* X, const float* Y, int N, SmemFused& s, int tid) {
  float xlo = 3.4e38f, xhi = -3.4e38f, ylo = 3.4e38f, yhi = -3.4e38f;
  for (int i = tid; i < N; i += 512) {
    float xv = X[i], yv = Y[i];
    xlo = fminf(xlo, xv); xhi = fmaxf(xhi, xv);
    ylo = fminf(ylo, yv); yhi = fmaxf(yhi, yv);
  }
  xlo = blockReduce<1>(xlo, s.red, tid);
  xhi = blockReduce<2>(xhi, s.red, tid);
  ylo = blockReduce<1>(ylo, s.red, tid);
  yhi = blockReduce<2>(yhi, s.red, tid);
  float xinv = 1.f / (xhi - xlo + 1e-6f);
  float yinv = 1.f / (yhi - ylo + 1e-6f);

  int bin = tid >> 3, sub = tid & 7;          // 64 bins x 8 sub-threads
  float c = (float)bin * (1.f / 63.f);
  float hxp = 0.f, hyp = 0.f;
  for (int i = sub; i < N; i += 8) {
    float dx = (X[i] - xlo) * xinv - c;
    float dy = (Y[i] - ylo) * yinv - c;
    hxp += __expf(-200.f * dx * dx);
    hyp += __expf(-200.f * dy * dy);
  }
  s.part[tid] = hxp;
  s.part[1024 + tid] = hyp;
  __syncthreads();
  if (tid < NBINS) {
    float hx = 1e-6f, hy = 1e-6f;
#pragma unroll
    for (int t = 0; t < 8; ++t) {
      hx += s.part[tid * 8 + t];
      hy += s.part[1024 + tid * 8 + t];
    }
    s.hx[tid] = hx; s.hy[tid] = hy;
  }
  __syncthreads();
  if (tid == 0) {
    float totx = 0.f, toty = 0.f;
    for (int b2 = 0; b2 < NBINS; ++b2) { totx += s.hx[b2]; toty += s.hy[b2]; }
    float ix = 1.f / totx, iy = 1.f / toty;
    float cx = 0.f, cy = 0.f;
    for (int b2 = 0; b2 < NBINS; ++b2) {
      cx += s.hx[b2] * ix; cy += s.hy[b2] * iy;
      s.hx[b2] = cx; s.hy[b2] = cy;
    }
  }
  __syncthreads();
  float p = 0.f;
  if (tid < NBINS) { float d = s.hx[tid] - s.hy[tid]; p = d * d; }
  return blockReduce<0>(p, s.red, tid);
}

// ---------------- db4 wavelet map (512 threads) ----------------
__device__ void wavelet_map(const float* row1024, float* fm, SmemFused& s, int tid, bool doEnergy) {
  const float LOF[8] = {-0.010597401784997278f, 0.032883011666982945f, 0.030841381835986965f,
                        -0.18703481171888114f, -0.02798376941698385f, 0.6308807679295904f,
                        0.7148465705525415f, 0.23037781330885523f};
  const float HIF[8] = {0.23037781330885523f, -0.7148465705525415f, 0.6308807679295904f,
                        0.02798376941698385f, -0.18703481171888114f, -0.030841381835986965f,
                        0.032883011666982945f, 0.010597401784997278f};
  const float* ain = row1024;
  int Lin = 1024;
  for (int lvl = 0; lvl < 5; ++lvl) {
    int Lout = Lin >> 1;                 // 512,256,128,64,32
    float* aout = (lvl & 1) ? s.aA : s.aB;
    float d = 0.f, a = 0.f;
    if (tid < Lout) {
#pragma unroll
      for (int kk = 0; kk < 8; ++kk) {
        int idx = 2 * tid + kk - 3;      // stride 2, SAME pad
        float v = (idx >= 0 && idx < Lin) ? ain[idx] : 0.f;
        d = fmaf(v, HIF[kk], d);
        a = fmaf(v, LOF[kk], a);
      }
      aout[tid] = a;
    }
    fm[lvl * 1024 + tid] = (tid < Lout) ? d : 0.f;
    fm[lvl * 1024 + tid + 512] = 0.f;
    if (doEnergy) {
      float e = (tid < Lout) ? fabsf(d) : 0.f;
      float se = blockReduce<0>(e, s.red, tid);
      if (tid == 0) s.energy[lvl] = se * (1.f / 1024.f);
    }
    __syncthreads();
    ain = aout; Lin = Lout;
  }
}

// ---------------- main fused kernel: 192 blocks x 512 threads ----------------
__global__ __launch_bounds__(512)
void mdl_main(const float* __restrict__ pred, const float* __restrict__ tgt,
              float* __restrict__ ws) {
  __shared__ SmemU sm;
  const int blk = blockIdx.x;
  const int tid = threadIdx.x;

  if (blk < 128) {
    // ==== soft-DTW: G=2, 32-diag unrolled chunks, all LDS hoisted to chunk edges ====
    SmemDtw& s = sm.d;
    const int mode = blk >> 6;          // 0: raw (T=1024), 1: 2nd derivative (T=1022)
    const int b = blk & 63;
    const int T = mode ? TSD : TFULL;
    const float* xr = pred + b * 1024;
    const float* yr = tgt + b * 1024;

    // stage y (pre-scaled) with BIG pads; init boundary buffers
    for (int i = tid; i < 1408; i += 512) {
      int j = i - 128;                   // 0-based y index
      float v = YPADV;
      if (j >= 0 && j < T)
        v = (mode ? (yr[j + 2] - 2.f * yr[j + 1] + yr[j]) : yr[j]) * SQ;
      s.ys[i] = v;
    }
    for (int i = tid; i < 8 * 3 * 32; i += 512) (&s.bnd[0][0][0])[i] = BIGS;

    // x registers: thread owns rows iA=2t+1, iB=2t+2 (1-based)
    const int iA = 2 * tid + 1, iB = iA + 1;
    float xA = YPADV, xB = YPADV;
    if (iA <= T) xA = (mode ? (xr[iA + 1] - 2.f * xr[iA] + xr[iA - 1]) : xr[iA - 1]) * SQ;
    if (iB <= T) xB = (mode ? (xr[iB + 1] - 2.f * xr[iB] + xr[iB - 1]) : xr[iB - 1]) * SQ;
    __syncthreads();

    const int w = tid >> 6, lane = tid & 63;
    const int c_begin = 4 * w;
    const int c_end = (min(128 * w + 128, T) + T - 2) >> 5;
    const int M = ((min(1024, T) + T - 2) >> 5) + 8;     // 71
    const int twoT = 2 * T;
    const bool isTarget = (tid == ((T - 2) >> 1));

    float a1 = BIGS, a2 = BIGS, b1 = BIGS;
    float nprev = (w == 0 && lane == 0) ? 0.f : BIGS;    // R[0,0] seed
    float ans = 0.f;

    for (int m = 0; m < M; ++m) {
      const int c = m - w;
      if (c >= c_begin && c <= c_end) {
        const int k0 = 2 + (c << 5);
        const int yidx0 = k0 - 2 * tid - 2 + 128;        // even by construction
        // ---- bulk LDS loads (only memory ops touching the recurrence) ----
        float yw[CH], rv[CH];
        float yprev = s.ys[yidx0 - 1];
#pragma unroll
        for (int q = 0; q < 16; ++q) {
          float2 t2 = *(const float2*)&s.ys[yidx0 + 2 * q];
          yw[2 * q] = t2.x; yw[2 * q + 1] = t2.y;
        }
        float rv0;
        if (w > 0) {
          const int cm = c % 3, cp = (c + 2) % 3;
          rv0 = s.bnd[w - 1][cp][31];
#pragma unroll
          for (int q = 0; q < 8; ++q) {
            float4 t4 = *(const float4*)&s.bnd[w - 1][cm][4 * q];
            rv[4 * q] = t4.x; rv[4 * q + 1] = t4.y;
            rv[4 * q + 2] = t4.z; rv[4 * q + 3] = t4.w;
          }
        } else {
          rv0 = BIGS;
#pragma unroll
          for (int q = 0; q < CH; ++q) rv[q] = BIGS;
        }
        float* wring = &s.bnd[w][c % 3][0];
        float yB = yprev;
        // ---- 32 diagonals, pure register/VALU ----
#pragma unroll
        for (int j = 0; j < CH; ++j) {
          float rvj = (j == 0) ? rv0 : rv[j - 1];
          // lane l <- lane l-1's b1; lane 0 <- rvj (old operand)
          float nb = __int_as_float(__builtin_amdgcn_update_dpp(
              __float_as_int(rvj), __float_as_int(b1),
              0x138 /*WAVE_SHR1*/, 0xF, 0xF, false));
          float yA = yw[j];
          // cell B (row iB): deps a1,b1,a2
          float dB = xB - yB;
          float mnB = fminf(fminf(a1, b1), a2);
          float mdB = __builtin_amdgcn_fmed3f(a1, b1, a2);
          float mxB = fmaxf(fmaxf(a1, b1), a2);
          float eB = 1.f + exp2f(mnB - mdB) + exp2f(mnB - mxB);
          float dkB = fmaf(dB, dB, mnB) - log2f(eB);
          // cell A (row iA): deps nb, a1, nprev
          float dA = xA - yA;
          float mnA = fminf(fminf(nb, a1), nprev);
          float mdA = __builtin_amdgcn_fmed3f(nb, a1, nprev);
          float mxA = fmaxf(fmaxf(nb, a1), nprev);
          float eA = 1.f + exp2f(mnA - mdA) + exp2f(mnA - mxA);
          float dkA = fmaf(dA, dA, mnA) - log2f(eA);
          if (lane == 63) wring[j] = dkB;               // boundary for next wave
          if (k0 + j == twoT) ans = isTarget ? dkB : ans;  // capture R[T,T]
          nprev = nb; a2 = a1; a1 = dkA; b1 = dkB; yB = yA;
        }
      }
      __syncthreads();
    }
    if (isTarget) ws[blk] = ans * GAMLN2;
  } else {
    // =================== fused per-batch losses (512 threads) ===================
    SmemFused& s = sm.f;
    const int b = blk - 128;
    const float* xg = pred + b * 1024;
    const float* yg = tgt + b * 1024;
    s.xr[tid] = xg[tid];        s.yr[tid] = yg[tid];
    s.xr[tid + 512] = xg[tid + 512]; s.yr[tid + 512] = yg[tid + 512];
    __syncthreads();

    // second derivative rows, aliased onto fmp region
    float* sdx = s.fmp;
    float* sdy = s.fmp + 1024;
    float spdacc = 0.f;
    for (int i = tid; i < TSD; i += 512) {
      float a = s.xr[i + 2] - 2.f * s.xr[i + 1] + s.xr[i];
      float cc = s.yr[i + 2] - 2.f * s.yr[i + 1] + s.yr[i];
      sdx[i] = a; sdy[i] = cc;
      spdacc += fabsf(a);
    }
    float spp = blockReduce<0>(fabsf(s.xr[tid]) + fabsf(s.xr[tid + 512]), s.red, tid);
    float spd = blockReduce<0>(spdacc, s.red, tid);   // barriers make sdx/sdy visible

    float c1 = cdf_pair(s.xr, s.yr, 1024, s, tid);
    float c2 = cdf_pair(sdx, sdy, TSD, s, tid);

    wavelet_map(s.xr, s.fmp, s, tid, true);
    wavelet_map(s.yr, s.fmt, s, tid, false);

    __syncthreads();
    if (tid == 0) {
      float e[5] = {s.energy[0], s.energy[1], s.energy[2], s.energy[3], s.energy[4]};
      int peak = 0; float best = e[0];
#pragma unroll
      for (int l = 1; l < 5; ++l) if (e[l] > best) { best = e[l]; peak = l; }
      float tot = 0.f, sel = 0.f;
#pragma unroll
      for (int l = 0; l < 5; ++l) {
        tot += e[l];
        if (l >= peak - 2 && l <= peak + 2) sel += e[l];
      }
      s.energy[7] = 1.f - sel / (tot + 1e-6f);
    }
    __syncthreads();
    float fr = s.energy[7];

    float c3 = cdf_pair(s.fmp, s.fmt, 5120, s, tid);

    if (tid == 0) {
      float* o = ws + 256 + b * 8;
      o[0] = c1; o[1] = c2; o[2] = c3;
      o[3] = fr; o[4] = spp; o[5] = spd;
    }
  }
}

// ---------------- final combine: 1 block x 64 threads ----------------
__global__ void mdl_combine(const float* __restrict__ ws, float* __restrict__ out) {
  const int lane = threadIdx.x;
  float vt = ws[lane];               // dtw time partial (batch=lane)
  float vs = ws[64 + lane];          // dtw sd partial
  const float* p = ws + 256 + lane * 8;
  float c1 = p[0], c2 = p[1], c3 = p[2], fr = p[3], sp = p[4], spd = p[5];
  vt = waveReduceSum(vt);  vs = waveReduceSum(vs);
  c1 = waveReduceSum(c1);  c2 = waveReduceSum(c2);  c3 = waveReduceSum(c3);
  fr = waveReduceSum(fr);  sp = waveReduceSum(sp);  spd = waveReduceSum(spd);
  if (lane == 0) {
    float dtw_t = vt * (1.f / 64.f);
    float dtw_s = vs * (1.f / 64.f);
    float l_time = dtw_t + sp * (1.f / 65536.f) + c1 * (1.f / 4096.f);
    float l_sd   = dtw_s + spd * (1.f / 65408.f) + c2 * (1.f / 4096.f);
    float l_freq = fr * (1.f / 64.f) + c3 * (1.f / 4096.f);
    float total = 1.5f * l_time + 0.8f * l_freq + 1.2f * l_sd;
    out[0] = total; out[1] = l_time; out[2] = l_freq; out[3] = l_sd;
  }
}

extern "C" void kernel_launch(void* const* d_in, const int* in_sizes, int n_in,
                              void* d_out, int out_size, void* d_ws, size_t ws_size,
                              hipStream_t stream) {
  const float* pred = (const float*)d_in[0];
  const float* tgt  = (const float*)d_in[1];
  float* out = (float*)d_out;
  float* ws  = (float*)d_ws;
  mdl_main<<<dim3(192), dim3(512), 0, stream>>>(pred, tgt, ws);
  mdl_combine<<<dim3(1), dim3(64), 0, stream>>>(ws, out);
}

// Round 6
// 430.170 us; speedup vs baseline: 1.5767x; 1.0561x over previous
//
#include <hip/hip_runtime.h>
#include <math.h>

#define BIGS  1.0e8f           // sentinel in scaled units
#define YPADV 12000.0f         // pad value: cost >= ~1.4e8 acts as BIG
#define TFULL 1024
#define TSD   1022
#define NBINS 64
#define CH    32               // diagonals per chunk (fully unrolled)
#define SQ    3.79828185f      // sqrt(1/(0.1*ln2)): cost_scaled = ((x-y)*SQ)^2
#define GAMLN2 0.069314718f    // 0.1*ln2: unscale factor

// ws float layout:
//  [0..127]       DTW results (q = mode*64 + b)
//  [256..767]     fused partials (b*8 + slot)
//  [1280..1407]   flags (int, one per q)
//  [1536..263679] gbnd: q*2048 + c*32 + j   (128 problems x 64 chunks x 32)
#define WS_PART  256
#define WS_FLAG  1280
#define WS_GBND  1536

// ---------------- shared memory layouts (union, <64KB) ----------------
struct SmemDtw {
  float ys[1408];              // [128 front pad][y][back pad], pre-scaled
  float bnd[8][3][32];         // per-local-wave chunk boundary buffers (mod 3)
};
struct SmemFused {
  float xr[1024], yr[1024];
  float fmp[5 * 1024], fmt[5 * 1024];
  float aA[512], aB[512];
  float part[2048];
  float hx[NBINS], hy[NBINS];
  float red[8];
  float energy[8];
};
union SmemU { SmemDtw d; SmemFused f; };

// ---------------- reductions ----------------
__device__ __forceinline__ float waveReduceSum(float v) {
#pragma unroll
  for (int o = 32; o > 0; o >>= 1) v += __shfl_xor(v, o, 64);
  return v;
}

template <int OP>  // 0=sum 1=min 2=max
__device__ __forceinline__ float comb2(float a, float b) {
  if (OP == 0) return a + b;
  if (OP == 1) return fminf(a, b);
  return fmaxf(a, b);
}

template <int OP>
__device__ float blockReduce(float v, float* red, int tid) {
#pragma unroll
  for (int o = 32; o > 0; o >>= 1) v = comb2<OP>(v, __shfl_xor(v, o, 64));
  __syncthreads();
  if ((tid & 63) == 0) red[tid >> 6] = v;
  __syncthreads();
  if (tid == 0) {
    float r = red[0];
#pragma unroll
    for (int w = 1; w < 8; ++w) r = comb2<OP>(r, red[w]);
    red[0] = r;
  }
  __syncthreads();
  return red[0];
}

// ---------------- cdf_variance partial (512 threads) ----------------
__device__ float cdf_pair(const float* X, const float* Y, int N, SmemFused& s, int tid) {
  float xlo = 3.4e38f, xhi = -3.4e38f, ylo = 3.4e38f, yhi = -3.4e38f;
  for (int i = tid; i < N; i += 512) {
    float xv = X[i], yv = Y[i];
    xlo = fminf(xlo, xv); xhi = fmaxf(xhi, xv);
    ylo = fminf(ylo, yv); yhi = fmaxf(yhi, yv);
  }
  xlo = blockReduce<1>(xlo, s.red, tid);
  xhi = blockReduce<2>(xhi, s.red, tid);
  ylo = blockReduce<1>(ylo, s.red, tid);
  yhi = blockReduce<2>(yhi, s.red, tid);
  float xinv = 1.f / (xhi - xlo + 1e-6f);
  float yinv = 1.f / (yhi - ylo + 1e-6f);

  int bin = tid >> 3, sub = tid & 7;          // 64 bins x 8 sub-threads
  float c = (float)bin * (1.f / 63.f);
  float hxp = 0.f, hyp = 0.f;
  for (int i = sub; i < N; i += 8) {
    float dx = (X[i] - xlo) * xinv - c;
    float dy = (Y[i] - ylo) * yinv - c;
    hxp += __expf(-200.f * dx * dx);
    hyp += __expf(-200.f * dy * dy);
  }
  s.part[tid] = hxp;
  s.part[1024 + tid] = hyp;
  __syncthreads();
  if (tid < NBINS) {
    float hx = 1e-6f, hy = 1e-6f;
#pragma unroll
    for (int t = 0; t < 8; ++t) {
      hx += s.part[tid * 8 + t];
      hy += s.part[1024 + tid * 8 + t];
    }
    s.hx[tid] = hx; s.hy[tid] = hy;
  }
  __syncthreads();
  if (tid == 0) {
    float totx = 0.f, toty = 0.f;
    for (int b2 = 0; b2 < NBINS; ++b2) { totx += s.hx[b2]; toty += s.hy[b2]; }
    float ix = 1.f / totx, iy = 1.f / toty;
    float cx = 0.f, cy = 0.f;
    for (int b2 = 0; b2 < NBINS; ++b2) {
      cx += s.hx[b2] * ix; cy += s.hy[b2] * iy;
      s.hx[b2] = cx; s.hy[b2] = cy;
    }
  }
  __syncthreads();
  float p = 0.f;
  if (tid < NBINS) { float d = s.hx[tid] - s.hy[tid]; p = d * d; }
  return blockReduce<0>(p, s.red, tid);
}

// ---------------- db4 wavelet map (512 threads) ----------------
__device__ void wavelet_map(const float* row1024, float* fm, SmemFused& s, int tid, bool doEnergy) {
  const float LOF[8] = {-0.010597401784997278f, 0.032883011666982945f, 0.030841381835986965f,
                        -0.18703481171888114f, -0.02798376941698385f, 0.6308807679295904f,
                        0.7148465705525415f, 0.23037781330885523f};
  const float HIF[8] = {0.23037781330885523f, -0.7148465705525415f, 0.6308807679295904f,
                        0.02798376941698385f, -0.18703481171888114f, -0.030841381835986965f,
                        0.032883011666982945f, 0.010597401784997278f};
  const float* ain = row1024;
  int Lin = 1024;
  for (int lvl = 0; lvl < 5; ++lvl) {
    int Lout = Lin >> 1;                 // 512,256,128,64,32
    float* aout = (lvl & 1) ? s.aA : s.aB;
    float d = 0.f, a = 0.f;
    if (tid < Lout) {
#pragma unroll
      for (int kk = 0; kk < 8; ++kk) {
        int idx = 2 * tid + kk - 3;      // stride 2, SAME pad
        float v = (idx >= 0 && idx < Lin) ? ain[idx] : 0.f;
        d = fmaf(v, HIF[kk], d);
        a = fmaf(v, LOF[kk], a);
      }
      aout[tid] = a;
    }
    fm[lvl * 1024 + tid] = (tid < Lout) ? d : 0.f;
    fm[lvl * 1024 + tid + 512] = 0.f;
    if (doEnergy) {
      float e = (tid < Lout) ? fabsf(d) : 0.f;
      float se = blockReduce<0>(e, s.red, tid);
      if (tid == 0) s.energy[lvl] = se * (1.f / 1024.f);
    }
    __syncthreads();
    ain = aout; Lin = Lout;
  }
}

// ------------- main fused kernel: 320 blocks x 512 threads -------------
// blocks [0,64): fused per-batch losses.  [64,192): DTW half A (rows 1..512).
// [192,320): DTW half B (rows 513..1024) — consumes A's boundary via global ring.
__global__ __launch_bounds__(512, 4)
void mdl_main(const float* __restrict__ pred, const float* __restrict__ tgt,
              float* __restrict__ ws) {
  __shared__ SmemU sm;
  const int p = blockIdx.x;
  const int tid = threadIdx.x;

  if (p >= 64) {
    // ===== soft-DTW: G=1, 2-CU split, 32-diag unrolled chunks =====
    SmemDtw& s = sm.d;
    const int half = (p >= 192) ? 1 : 0;
    const int q = half ? (p - 192) : (p - 64);
    const int mode = q >> 6;            // 0: raw (T=1024), 1: 2nd deriv (T=1022)
    const int b = q & 63;
    const int T = mode ? TSD : TFULL;
    const float* xr = pred + b * 1024;
    const float* yr = tgt + b * 1024;

    for (int i = tid; i < 1408; i += 512) {
      int j = i - 128;
      float v = YPADV;
      if (j >= 0 && j < T)
        v = (mode ? (yr[j + 2] - 2.f * yr[j + 1] + yr[j]) : yr[j]) * SQ;
      s.ys[i] = v;
    }
    for (int i = tid; i < 8 * 3 * 32; i += 512) (&s.bnd[0][0][0])[i] = BIGS;

    const int w = tid >> 6, lane = tid & 63;
    const int W = half * 8 + w;          // global wave id (0..15)
    const int g = half * 512 + tid;      // row-1 (thread owns row g+1)
    float xv = YPADV;
    if (g < T) xv = (mode ? (xr[g + 2] - 2.f * xr[g + 1] + xr[g]) : xr[g]) * SQ;
    __syncthreads();

    const int c_begin = 2 * W;
    const int c_end = (min(64 * W + 64, T) + T - 2) >> 5;
    const int prodEnd = (512 + T - 2) >> 5;          // A wave7's last chunk (47)
    const int twoT = 2 * T;
    const int M = (half ? ((twoT - 2) >> 5) : prodEnd) + 8;
    const bool toGlobal = (half == 0 && w == 7);
    const bool fromGlobal = (half == 1 && w == 0);
    float* gb = ws + WS_GBND + q * 2048;             // 64 chunks x 32
    int* flagp = (int*)(ws + WS_FLAG) + q;

    float prev1 = BIGS;                               // own R at k-1
    float n2 = (half == 0 && w == 0 && lane == 0) ? 0.f : BIGS;  // nbr at k-2
    float ans = 0.f;
    const bool isTarget = (half == 1) && (tid == (T - 1 - 512));

    for (int m = 0; m < M; ++m) {
      const int c = m - w;
      if (c >= c_begin && c <= c_end) {
        const int k0 = 2 + (c << 5);
        const int yidx0 = k0 - g - 2 + 128;
        float rv[CH], rv0;
        if (fromGlobal) {
          if (c <= prodEnd) {
            while (__hip_atomic_load(flagp, __ATOMIC_ACQUIRE,
                                     __HIP_MEMORY_SCOPE_AGENT) < c + 1)
              __builtin_amdgcn_s_sleep(2);
            rv0 = gb[c * 32 - 1];
#pragma unroll
            for (int qq = 0; qq < 8; ++qq) {
              float4 t4 = *(const float4*)&gb[c * 32 + 4 * qq];
              rv[4 * qq] = t4.x; rv[4 * qq + 1] = t4.y;
              rv[4 * qq + 2] = t4.z; rv[4 * qq + 3] = t4.w;
            }
          } else {
            rv0 = BIGS;
#pragma unroll
            for (int qq = 0; qq < CH; ++qq) rv[qq] = BIGS;
          }
        } else if (w > 0) {
          const int cm = c % 3;
          rv0 = s.bnd[w - 1][(c + 2) % 3][31];
#pragma unroll
          for (int qq = 0; qq < 8; ++qq) {
            float4 t4 = *(const float4*)&s.bnd[w - 1][cm][4 * qq];
            rv[4 * qq] = t4.x; rv[4 * qq + 1] = t4.y;
            rv[4 * qq + 2] = t4.z; rv[4 * qq + 3] = t4.w;
          }
        } else {
          rv0 = BIGS;
#pragma unroll
          for (int qq = 0; qq < CH; ++qq) rv[qq] = BIGS;
        }
        float* lring = &s.bnd[w][c % 3][0];
        float* gring = gb + c * 32;
        // ---- 32 diagonals, pure register/VALU ----
#pragma unroll
        for (int j = 0; j < CH; ++j) {
          float rvj = (j == 0) ? rv0 : rv[j - 1];
          // lane l <- lane l-1's prev1 (nbr dk at k-1); lane 0 <- rvj
          float nb = __int_as_float(__builtin_amdgcn_update_dpp(
              __float_as_int(rvj), __float_as_int(prev1),
              0x138 /*WAVE_SHR1*/, 0xF, 0xF, false));
          float yv = s.ys[yidx0 + j];
          float d = xv - yv;
          float mn = fminf(fminf(nb, prev1), n2);
          float md = __builtin_amdgcn_fmed3f(nb, prev1, n2);
          float mx = fmaxf(fmaxf(nb, prev1), n2);
          float e = 1.f + exp2f(mn - md) + exp2f(mn - mx);
          float dk = fmaf(d, d, mn) - log2f(e);
          if (lane == 63) {
            if (toGlobal) gring[j] = dk; else lring[j] = dk;
          }
          if (k0 + j == twoT) ans = isTarget ? dk : ans;
          n2 = nb; prev1 = dk;
        }
        if (toGlobal && lane == 63)
          __hip_atomic_store(flagp, c + 1, __ATOMIC_RELEASE,
                             __HIP_MEMORY_SCOPE_AGENT);
      }
      __syncthreads();
    }
    if (isTarget) ws[q] = ans * GAMLN2;
  } else {
    // =================== fused per-batch losses (512 threads) ===================
    SmemFused& s = sm.f;
    const int b = p;
    const float* xg = pred + b * 1024;
    const float* yg = tgt + b * 1024;
    s.xr[tid] = xg[tid];             s.yr[tid] = yg[tid];
    s.xr[tid + 512] = xg[tid + 512]; s.yr[tid + 512] = yg[tid + 512];
    __syncthreads();

    float* sdx = s.fmp;
    float* sdy = s.fmp + 1024;
    float spdacc = 0.f;
    for (int i = tid; i < TSD; i += 512) {
      float a = s.xr[i + 2] - 2.f * s.xr[i + 1] + s.xr[i];
      float cc = s.yr[i + 2] - 2.f * s.yr[i + 1] + s.yr[i];
      sdx[i] = a; sdy[i] = cc;
      spdacc += fabsf(a);
    }
    float spp = blockReduce<0>(fabsf(s.xr[tid]) + fabsf(s.xr[tid + 512]), s.red, tid);
    float spd = blockReduce<0>(spdacc, s.red, tid);

    float c1 = cdf_pair(s.xr, s.yr, 1024, s, tid);
    float c2 = cdf_pair(sdx, sdy, TSD, s, tid);

    wavelet_map(s.xr, s.fmp, s, tid, true);
    wavelet_map(s.yr, s.fmt, s, tid, false);

    __syncthreads();
    if (tid == 0) {
      float e[5] = {s.energy[0], s.energy[1], s.energy[2], s.energy[3], s.energy[4]};
      int peak = 0; float best = e[0];
#pragma unroll
      for (int l = 1; l < 5; ++l) if (e[l] > best) { best = e[l]; peak = l; }
      float tot = 0.f, sel = 0.f;
#pragma unroll
      for (int l = 0; l < 5; ++l) {
        tot += e[l];
        if (l >= peak - 2 && l <= peak + 2) sel += e[l];
      }
      s.energy[7] = 1.f - sel / (tot + 1e-6f);
    }
    __syncthreads();
    float fr = s.energy[7];

    float c3 = cdf_pair(s.fmp, s.fmt, 5120, s, tid);

    if (tid == 0) {
      float* o = ws + WS_PART + b * 8;
      o[0] = c1; o[1] = c2; o[2] = c3;
      o[3] = fr; o[4] = spp; o[5] = spd;
    }
  }
}

// ---------------- final combine: 1 block x 64 threads ----------------
__global__ void mdl_combine(const float* __restrict__ ws, float* __restrict__ out) {
  const int lane = threadIdx.x;
  float vt = ws[lane];               // dtw time partial (batch=lane)
  float vs = ws[64 + lane];          // dtw sd partial
  const float* pp = ws + WS_PART + lane * 8;
  float c1 = pp[0], c2 = pp[1], c3 = pp[2], fr = pp[3], sp = pp[4], spd = pp[5];
  vt = waveReduceSum(vt);  vs = waveReduceSum(vs);
  c1 = waveReduceSum(c1);  c2 = waveReduceSum(c2);  c3 = waveReduceSum(c3);
  fr = waveReduceSum(fr);  sp = waveReduceSum(sp);  spd = waveReduceSum(spd);
  if (lane == 0) {
    float dtw_t = vt * (1.f / 64.f);
    float dtw_s = vs * (1.f / 64.f);
    float l_time = dtw_t + sp * (1.f / 65536.f) + c1 * (1.f / 4096.f);
    float l_sd   = dtw_s + spd * (1.f / 65408.f) + c2 * (1.f / 4096.f);
    float l_freq = fr * (1.f / 64.f) + c3 * (1.f / 4096.f);
    float total = 1.5f * l_time + 0.8f * l_freq + 1.2f * l_sd;
    out[0] = total; out[1] = l_time; out[2] = l_freq; out[3] = l_sd;
  }
}

extern "C" void kernel_launch(void* const* d_in, const int* in_sizes, int n_in,
                              void* d_out, int out_size, void* d_ws, size_t ws_size,
                              hipStream_t stream) {
  const float* pred = (const float*)d_in[0];
  const float* tgt  = (const float*)d_in[1];
  float* out = (float*)d_out;
  float* ws  = (float*)d_ws;
  // zero the cross-block handoff flags (re-poisoned to 0xAA before every launch)
  hipMemsetAsync((char*)d_ws + WS_FLAG * 4, 0, 128 * sizeof(int), stream);
  mdl_main<<<dim3(320), dim3(512), 0, stream>>>(pred, tgt, ws);
  mdl_combine<<<dim3(1), dim3(64), 0, stream>>>(ws, out);
}

// Round 7
// 428.095 us; speedup vs baseline: 1.5843x; 1.0048x over previous
//
#include <hip/hip_runtime.h>
#include <math.h>

#define BIGS  1.0e8f           // sentinel in scaled units
#define YPADV 12000.0f         // pad value: cost >= ~1.4e8 acts as BIG
#define TFULL 1024
#define TSD   1022
#define NBINS 64
#define CH    32               // diagonals per chunk (fully unrolled)
#define SQ    3.79828185f      // sqrt(1/(0.1*ln2)): cost_scaled = ((x-y)*SQ)^2
#define GAMLN2 0.069314718f    // 0.1*ln2: unscale factor

// ws float layout:
//  [0..127]       DTW results (q = mode*64 + b)
//  [256..767]     fused partials (b*8 + slot)
//  [1280..1407]   flags (int, one per q)
//  [1536..263679] gbnd: q*2048 + c*32 + j   (128 problems x 64 chunks x 32)
#define WS_PART  256
#define WS_FLAG  1280
#define WS_GBND  1536

// ---------------- shared memory layouts (union, <64KB) ----------------
struct SmemDtw {
  float ys[1408];              // [128 front pad][y][back pad], pre-scaled
  float bnd[8][3][32];         // per-local-wave chunk boundary buffers (mod 3)
};
struct SmemFused {
  float xr[1024], yr[1024];
  float fmp[5 * 1024], fmt[5 * 1024];
  float aA[512], aB[512];
  float part[2048];
  float hx[NBINS], hy[NBINS];
  float red[8];
  float energy[8];
};
union SmemU { SmemDtw d; SmemFused f; };

// ---------------- reductions ----------------
__device__ __forceinline__ float waveReduceSum(float v) {
#pragma unroll
  for (int o = 32; o > 0; o >>= 1) v += __shfl_xor(v, o, 64);
  return v;
}

template <int OP>  // 0=sum 1=min 2=max
__device__ __forceinline__ float comb2(float a, float b) {
  if (OP == 0) return a + b;
  if (OP == 1) return fminf(a, b);
  return fmaxf(a, b);
}

template <int OP>
__device__ float blockReduce(float v, float* red, int tid) {
#pragma unroll
  for (int o = 32; o > 0; o >>= 1) v = comb2<OP>(v, __shfl_xor(v, o, 64));
  __syncthreads();
  if ((tid & 63) == 0) red[tid >> 6] = v;
  __syncthreads();
  if (tid == 0) {
    float r = red[0];
#pragma unroll
    for (int w = 1; w < 8; ++w) r = comb2<OP>(r, red[w]);
    red[0] = r;
  }
  __syncthreads();
  return red[0];
}

// ---------------- cdf_variance partial (512 threads) ----------------
__device__ float cdf_pair(const float* X, const float* Y, int N, SmemFused& s, int tid) {
  float xlo = 3.4e38f, xhi = -3.4e38f, ylo = 3.4e38f, yhi = -3.4e38f;
  for (int i = tid; i < N; i += 512) {
    float xv = X[i], yv = Y[i];
    xlo = fminf(xlo, xv); xhi = fmaxf(xhi, xv);
    ylo = fminf(ylo, yv); yhi = fmaxf(yhi, yv);
  }
  xlo = blockReduce<1>(xlo, s.red, tid);
  xhi = blockReduce<2>(xhi, s.red, tid);
  ylo = blockReduce<1>(ylo, s.red, tid);
  yhi = blockReduce<2>(yhi, s.red, tid);
  float xinv = 1.f / (xhi - xlo + 1e-6f);
  float yinv = 1.f / (yhi - ylo + 1e-6f);

  int bin = tid >> 3, sub = tid & 7;          // 64 bins x 8 sub-threads
  float c = (float)bin * (1.f / 63.f);
  float hxp = 0.f, hyp = 0.f;
  for (int i = sub; i < N; i += 8) {
    float dx = (X[i] - xlo) * xinv - c;
    float dy = (Y[i] - ylo) * yinv - c;
    hxp += __expf(-200.f * dx * dx);
    hyp += __expf(-200.f * dy * dy);
  }
  s.part[tid] = hxp;
  s.part[1024 + tid] = hyp;
  __syncthreads();
  if (tid < NBINS) {
    float hx = 1e-6f, hy = 1e-6f;
#pragma unroll
    for (int t = 0; t < 8; ++t) {
      hx += s.part[tid * 8 + t];
      hy += s.part[1024 + tid * 8 + t];
    }
    s.hx[tid] = hx; s.hy[tid] = hy;
  }
  __syncthreads();
  if (tid == 0) {
    float totx = 0.f, toty = 0.f;
    for (int b2 = 0; b2 < NBINS; ++b2) { totx += s.hx[b2]; toty += s.hy[b2]; }
    float ix = 1.f / totx, iy = 1.f / toty;
    float cx = 0.f, cy = 0.f;
    for (int b2 = 0; b2 < NBINS; ++b2) {
      cx += s.hx[b2] * ix; cy += s.hy[b2] * iy;
      s.hx[b2] = cx; s.hy[b2] = cy;
    }
  }
  __syncthreads();
  float p = 0.f;
  if (tid < NBINS) { float d = s.hx[tid] - s.hy[tid]; p = d * d; }
  return blockReduce<0>(p, s.red, tid);
}

// ---------------- db4 wavelet map (512 threads) ----------------
__device__ void wavelet_map(const float* row1024, float* fm, SmemFused& s, int tid, bool doEnergy) {
  const float LOF[8] = {-0.010597401784997278f, 0.032883011666982945f, 0.030841381835986965f,
                        -0.18703481171888114f, -0.02798376941698385f, 0.6308807679295904f,
                        0.7148465705525415f, 0.23037781330885523f};
  const float HIF[8] = {0.23037781330885523f, -0.7148465705525415f, 0.6308807679295904f,
                        0.02798376941698385f, -0.18703481171888114f, -0.030841381835986965f,
                        0.032883011666982945f, 0.010597401784997278f};
  const float* ain = row1024;
  int Lin = 1024;
  for (int lvl = 0; lvl < 5; ++lvl) {
    int Lout = Lin >> 1;                 // 512,256,128,64,32
    float* aout = (lvl & 1) ? s.aA : s.aB;
    float d = 0.f, a = 0.f;
    if (tid < Lout) {
#pragma unroll
      for (int kk = 0; kk < 8; ++kk) {
        int idx = 2 * tid + kk - 3;      // stride 2, SAME pad
        float v = (idx >= 0 && idx < Lin) ? ain[idx] : 0.f;
        d = fmaf(v, HIF[kk], d);
        a = fmaf(v, LOF[kk], a);
      }
      aout[tid] = a;
    }
    fm[lvl * 1024 + tid] = (tid < Lout) ? d : 0.f;
    fm[lvl * 1024 + tid + 512] = 0.f;
    if (doEnergy) {
      float e = (tid < Lout) ? fabsf(d) : 0.f;
      float se = blockReduce<0>(e, s.red, tid);
      if (tid == 0) s.energy[lvl] = se * (1.f / 1024.f);
    }
    __syncthreads();
    ain = aout; Lin = Lout;
  }
}

// ------------- main fused kernel: 320 blocks x 512 threads -------------
// blocks [0,64): fused per-batch losses.  [64,192): DTW half A (rows 1..512).
// [192,320): DTW half B (rows 513..1024) — consumes A's boundary via global ring.
__global__ __launch_bounds__(512, 4)
void mdl_main(const float* __restrict__ pred, const float* __restrict__ tgt,
              float* __restrict__ ws) {
  __shared__ SmemU sm;
  const int p = blockIdx.x;
  const int tid = threadIdx.x;

  if (p >= 64) {
    // ===== soft-DTW: G=1, 2-CU split, 32-diag unrolled chunks =====
    SmemDtw& s = sm.d;
    const int half = (p >= 192) ? 1 : 0;
    const int q = half ? (p - 192) : (p - 64);
    const int mode = q >> 6;            // 0: raw (T=1024), 1: 2nd deriv (T=1022)
    const int b = q & 63;
    const int T = mode ? TSD : TFULL;
    const float* xr = pred + b * 1024;
    const float* yr = tgt + b * 1024;

    for (int i = tid; i < 1408; i += 512) {
      int j = i - 128;
      float v = YPADV;
      if (j >= 0 && j < T)
        v = (mode ? (yr[j + 2] - 2.f * yr[j + 1] + yr[j]) : yr[j]) * SQ;
      s.ys[i] = v;
    }
    for (int i = tid; i < 8 * 3 * 32; i += 512) (&s.bnd[0][0][0])[i] = BIGS;

    const int w = tid >> 6, lane = tid & 63;
    const int W = half * 8 + w;          // global wave id (0..15)
    const int g = half * 512 + tid;      // row-1 (thread owns row g+1)
    float xv = YPADV;
    if (g < T) xv = (mode ? (xr[g + 2] - 2.f * xr[g + 1] + xr[g]) : xr[g]) * SQ;
    __syncthreads();

    const int c_begin = 2 * W;
    const int c_end = (min(64 * W + 64, T) + T - 2) >> 5;
    const int prodEnd = (512 + T - 2) >> 5;          // A wave7's last chunk (47)
    const int twoT = 2 * T;
    const int M = (half ? ((twoT - 2) >> 5) : prodEnd) + 8;
    const bool toGlobal = (half == 0 && w == 7);
    const bool fromGlobal = (half == 1 && w == 0);
    float* gb = ws + WS_GBND + q * 2048;             // 64 chunks x 32
    int* flagp = (int*)(ws + WS_FLAG) + q;
    const int li = lane & 31;

    float prev1 = BIGS;                               // own R at k-1
    float n2 = (half == 0 && w == 0 && lane == 0) ? 0.f : BIGS;  // nbr at k-2
    float ans = 0.f;
    const bool isTarget = (half == 1) && (tid == (T - 1 - 512));

    for (int m = 0; m < M; ++m) {
      const int c = m - w;
      if (c >= c_begin && c <= c_end) {
        const int k0 = 2 + (c << 5);
        const int yidx0 = k0 - g - 2 + 128;
        // ---- bulk LDS y-loads (program-order BEFORE any ring write this chunk) ----
        float yw[CH];
#pragma unroll
        for (int j = 0; j < CH; ++j) yw[j] = s.ys[yidx0 + j];
        // ---- lane-striped boundary: lane l holds ring[c*32 - 1 + l] ----
        float rlane = BIGS;
        if (fromGlobal) {
          if (c <= prodEnd) {
            while (__hip_atomic_load(flagp, __ATOMIC_ACQUIRE,
                                     __HIP_MEMORY_SCOPE_AGENT) < c + 1)
              __builtin_amdgcn_s_sleep(1);
            rlane = gb[c * 32 - 1 + li];               // coalesced
          }
        } else if (w > 0) {
          const int cm = c % 3, cp = (c + 2) % 3;
          const float* rb = &s.bnd[w - 1][0][0];
          rlane = rb[li ? (cm * 32 + li - 1) : (cp * 32 + 31)];
        }
        float* lring = &s.bnd[w][c % 3][0];
        float* gring = gb + c * 32;
        // ---- 32 diagonals, pure register/VALU ----
#pragma unroll
        for (int j = 0; j < CH; ++j) {
          float rvj = __int_as_float(
              __builtin_amdgcn_readlane(__float_as_int(rlane), j));
          // lane l <- lane l-1's prev1 (nbr dk at k-1); lane 0 <- rvj
          float nb = __int_as_float(__builtin_amdgcn_update_dpp(
              __float_as_int(rvj), __float_as_int(prev1),
              0x138 /*WAVE_SHR1*/, 0xF, 0xF, false));
          float yv = yw[j];
          float d = xv - yv;
          float mn = fminf(fminf(nb, prev1), n2);
          float md = __builtin_amdgcn_fmed3f(nb, prev1, n2);
          float mx = fmaxf(fmaxf(nb, prev1), n2);
          float e = 1.f + exp2f(mn - md) + exp2f(mn - mx);
          float dk = fmaf(d, d, mn) - log2f(e);
          if (lane == 63) {
            if (toGlobal) gring[j] = dk; else lring[j] = dk;
          }
          if (k0 + j == twoT) ans = isTarget ? dk : ans;
          n2 = nb; prev1 = dk;
        }
        if (toGlobal && lane == 63)
          __hip_atomic_store(flagp, c + 1, __ATOMIC_RELEASE,
                             __HIP_MEMORY_SCOPE_AGENT);
      }
      __syncthreads();
    }
    if (isTarget) ws[q] = ans * GAMLN2;
  } else {
    // =================== fused per-batch losses (512 threads) ===================
    SmemFused& s = sm.f;
    const int b = p;
    const float* xg = pred + b * 1024;
    const float* yg = tgt + b * 1024;
    s.xr[tid] = xg[tid];             s.yr[tid] = yg[tid];
    s.xr[tid + 512] = xg[tid + 512]; s.yr[tid + 512] = yg[tid + 512];
    __syncthreads();

    float* sdx = s.fmp;
    float* sdy = s.fmp + 1024;
    float spdacc = 0.f;
    for (int i = tid; i < TSD; i += 512) {
      float a = s.xr[i + 2] - 2.f * s.xr[i + 1] + s.xr[i];
      float cc = s.yr[i + 2] - 2.f * s.yr[i + 1] + s.yr[i];
      sdx[i] = a; sdy[i] = cc;
      spdacc += fabsf(a);
    }
    float spp = blockReduce<0>(fabsf(s.xr[tid]) + fabsf(s.xr[tid + 512]), s.red, tid);
    float spd = blockReduce<0>(spdacc, s.red, tid);

    float c1 = cdf_pair(s.xr, s.yr, 1024, s, tid);
    float c2 = cdf_pair(sdx, sdy, TSD, s, tid);

    wavelet_map(s.xr, s.fmp, s, tid, true);
    wavelet_map(s.yr, s.fmt, s, tid, false);

    __syncthreads();
    if (tid == 0) {
      float e[5] = {s.energy[0], s.energy[1], s.energy[2], s.energy[3], s.energy[4]};
      int peak = 0; float best = e[0];
#pragma unroll
      for (int l = 1; l < 5; ++l) if (e[l] > best) { best = e[l]; peak = l; }
      float tot = 0.f, sel = 0.f;
#pragma unroll
      for (int l = 0; l < 5; ++l) {
        tot += e[l];
        if (l >= peak - 2 && l <= peak + 2) sel += e[l];
      }
      s.energy[7] = 1.f - sel / (tot + 1e-6f);
    }
    __syncthreads();
    float fr = s.energy[7];

    float c3 = cdf_pair(s.fmp, s.fmt, 5120, s, tid);

    if (tid == 0) {
      float* o = ws + WS_PART + b * 8;
      o[0] = c1; o[1] = c2; o[2] = c3;
      o[3] = fr; o[4] = spp; o[5] = spd;
    }
  }
}

// ---------------- final combine: 1 block x 64 threads ----------------
__global__ void mdl_combine(const float* __restrict__ ws, float* __restrict__ out) {
  const int lane = threadIdx.x;
  float vt = ws[lane];               // dtw time partial (batch=lane)
  float vs = ws[64 + lane];          // dtw sd partial
  const float* pp = ws + WS_PART + lane * 8;
  float c1 = pp[0], c2 = pp[1], c3 = pp[2], fr = pp[3], sp = pp[4], spd = pp[5];
  vt = waveReduceSum(vt);  vs = waveReduceSum(vs);
  c1 = waveReduceSum(c1);  c2 = waveReduceSum(c2);  c3 = waveReduceSum(c3);
  fr = waveReduceSum(fr);  sp = waveReduceSum(sp);  spd = waveReduceSum(spd);
  if (lane == 0) {
    float dtw_t = vt * (1.f / 64.f);
    float dtw_s = vs * (1.f / 64.f);
    float l_time = dtw_t + sp * (1.f / 65536.f) + c1 * (1.f / 4096.f);
    float l_sd   = dtw_s + spd * (1.f / 65408.f) + c2 * (1.f / 4096.f);
    float l_freq = fr * (1.f / 64.f) + c3 * (1.f / 4096.f);
    float total = 1.5f * l_time + 0.8f * l_freq + 1.2f * l_sd;
    out[0] = total; out[1] = l_time; out[2] = l_freq; out[3] = l_sd;
  }
}

extern "C" void kernel_launch(void* const* d_in, const int* in_sizes, int n_in,
                              void* d_out, int out_size, void* d_ws, size_t ws_size,
                              hipStream_t stream) {
  const float* pred = (const float*)d_in[0];
  const float* tgt  = (const float*)d_in[1];
  float* out = (float*)d_out;
  float* ws  = (float*)d_ws;
  // zero the cross-block handoff flags (re-poisoned to 0xAA before every launch)
  hipMemsetAsync((char*)d_ws + WS_FLAG * 4, 0, 128 * sizeof(int), stream);
  mdl_main<<<dim3(320), dim3(512), 0, stream>>>(pred, tgt, ws);
  mdl_combine<<<dim3(1), dim3(64), 0, stream>>>(ws, out);
}